// Round 12
// baseline (253.561 us; speedup 1.0000x reference)
//
#include <hip/hip_runtime.h>

#define TT 4
#define BB 8
#define CC 256
#define NN 512
#define HEADS 16
#define HD 16

#define GLL16(gp, lp) \
    __builtin_amdgcn_global_load_lds( \
        (const __attribute__((address_space(1))) void*)(gp), \
        (__attribute__((address_space(3))) void*)(lp), 16, 0, 0)

struct WPtrs  { const float* w[4]; };
struct BnPtrs { const float* g[4]; const float* b[4]; const float* m[4]; const float* v[4]; };

// -----------------------------------------------------------------------------
// Prep: transpose 4 weight matrices (wt[m][k][o] = w_m[o][k]) and, in the
// (0,0,m) blocks, compute BN affine (sc, bi). grid(16,16,4), block(16,16).
// -----------------------------------------------------------------------------
__global__ __launch_bounds__(256)
void prep_w_bn(WPtrs p, BnPtrs bp, float* __restrict__ wt,
               float* __restrict__ sc, float* __restrict__ bi)
{
    __shared__ float t[16][17];
    const int m  = blockIdx.z;
    const float* w = p.w[m];
    const int o0 = blockIdx.y * 16, k0 = blockIdx.x * 16;
    const int tx = threadIdx.x, ty = threadIdx.y;
    t[ty][tx] = w[(size_t)(o0 + ty) * CC + k0 + tx];
    if (blockIdx.x == 0 && blockIdx.y == 0) {
        int c = ty * 16 + tx;
        float rs = __fdiv_rn(1.0f, __fsqrt_rn(__fadd_rn(bp.v[m][c], 1e-5f)));
        float s  = __fmul_rn(bp.g[m][c], rs);
        sc[m * CC + c] = s;
        bi[m * CC + c] = __fsub_rn(bp.b[m][c], __fmul_rn(bp.m[m][c], s));
    }
    __syncthreads();
    wt[(size_t)m * CC * CC + (size_t)(k0 + ty) * CC + o0 + tx] = t[tx][ty];
}

// -----------------------------------------------------------------------------
// Kernel A: q/k/v conv + BN, T-PARALLEL. 128x128 tiles, 4 waves in 2x2
// quadrants of 64x64, 8x8 per thread; all LDS reads 8-distinct-addr (free).
// BK=16, 16 stages, double-buffered; LDS 32 KB -> 3 blocks/CU co-resident
// (grid 768 = (4,2,96)), 12 waves/CU. Writes BN'd pre-activations.
// -----------------------------------------------------------------------------
__global__ __launch_bounds__(256)
void qkv_gemm_bn(const float* __restrict__ x,     // [32][C][N]
                 const float* __restrict__ wt,    // [3][C][C] k-major
                 const float* __restrict__ scA,   // [4][C]
                 const float* __restrict__ biA,
                 float* __restrict__ ybn3)        // [3][32][C][N]
{
    __shared__ float Wl[2][16][128];   // 16 KB [k][o]
    __shared__ float Xl[2][16][128];   // 16 KB [k][n]

    const int tid  = threadIdx.x;
    const int wave = tid >> 6;
    const int lane = tid & 63;
    const int wr = wave >> 1;          // o-quadrant
    const int wc = wave & 1;           // n-quadrant
    const int ty = lane >> 3;          // 8 o-rows of 8
    const int tx = lane & 7;           // 8 n-cols of 8
    const int br = blockIdx.z >> 5;
    const int tb = blockIdx.z & 31;
    const int o0 = blockIdx.y * 128;
    const int n0 = blockIdx.x * 128;
    const int oo = o0 + wr * 64 + ty * 8;
    const int nn = n0 + wc * 64 + tx * 8;

    const float* wb = wt + (size_t)br * CC * CC;
    const float* xb = x + (size_t)tb * (CC * NN);

    auto stage = [&](int s, int buf) {
        const int k0 = s * 16;
#pragma unroll
        for (int i = 0; i < 2; ++i) {
            int idx = tid + 256 * i;          // 0..511 ; LDS linear at idx*16
            int row = idx >> 5, cg = idx & 31;
            GLL16(&wb[(size_t)(k0 + row) * CC + o0 + cg * 4], &Wl[buf][row][cg * 4]);
        }
#pragma unroll
        for (int i = 0; i < 2; ++i) {
            int idx = tid + 256 * i;
            int row = idx >> 5, cg = idx & 31;
            GLL16(&xb[(size_t)(k0 + row) * NN + n0 + cg * 4], &Xl[buf][row][cg * 4]);
        }
    };

    float acc[8][8];
#pragma unroll
    for (int i = 0; i < 8; ++i)
#pragma unroll
        for (int j = 0; j < 8; ++j) acc[i][j] = 0.0f;

    stage(0, 0);
    __syncthreads();

    int cur = 0;
    for (int s = 0; s < 16; ++s) {
        if (s < 15) stage(s + 1, cur ^ 1);

#pragma unroll 8
        for (int kk = 0; kk < 16; ++kk) {
            const float4 w0 = *reinterpret_cast<const float4*>(&Wl[cur][kk][wr * 64 + ty * 8]);
            const float4 w1 = *reinterpret_cast<const float4*>(&Wl[cur][kk][wr * 64 + ty * 8 + 4]);
            const float4 x0 = *reinterpret_cast<const float4*>(&Xl[cur][kk][wc * 64 + tx * 8]);
            const float4 x1 = *reinterpret_cast<const float4*>(&Xl[cur][kk][wc * 64 + tx * 8 + 4]);
            const float wa[8] = {w0.x, w0.y, w0.z, w0.w, w1.x, w1.y, w1.z, w1.w};
            const float xa[8] = {x0.x, x0.y, x0.z, x0.w, x1.x, x1.y, x1.z, x1.w};
#pragma unroll
            for (int i = 0; i < 8; ++i)
#pragma unroll
                for (int j = 0; j < 8; ++j)
                    acc[i][j] = __fmaf_rn(wa[i], xa[j], acc[i][j]);
        }

        __syncthreads();
        cur ^= 1;
    }

    float* Yp = ybn3 + ((size_t)br * 32 + tb) * (CC * NN);
#pragma unroll
    for (int i = 0; i < 8; ++i) {
        const float sc = scA[br * CC + oo + i];
        const float bi = biA[br * CC + oo + i];
        float r[8];
#pragma unroll
        for (int j = 0; j < 8; ++j)
            r[j] = __fadd_rn(__fmul_rn(acc[i][j], sc), bi);
        float* dst = &Yp[(size_t)(oo + i) * NN + nn];
        *reinterpret_cast<float4*>(dst)     = make_float4(r[0], r[1], r[2], r[3]);
        *reinterpret_cast<float4*>(dst + 4) = make_float4(r[4], r[5], r[6], r[7]);
    }
}

// -----------------------------------------------------------------------------
// Kernel B: q/k/v LIF(v_th=1) over T=4 + ballot bit-pack.
// grid 12288 x 256: thread g -> (br, b, c, n); lanes = 64 consecutive n.
// -----------------------------------------------------------------------------
__global__ __launch_bounds__(256)
void qkv_lif_pack(const float* __restrict__ ybn3,      // [3][32][C][N]
                  unsigned long long* __restrict__ bits) // [3][32*C*8]
{
    const int g = blockIdx.x * 256 + threadIdx.x;
    const int n = g & 511;
    const int c = (g >> 9) & 255;
    const int b = (g >> 17) & 7;
    const int br = g >> 20;

    const float* src = ybn3 + (size_t)br * 32 * (CC * NN);
    unsigned long long* bout = bits + (size_t)br * (32 * CC * 8);

    float v = 0.0f;
#pragma unroll
    for (int t = 0; t < 4; ++t) {
        const int tb = t * 8 + b;
        float xv = src[((size_t)tb * CC + c) * NN + n];
        float h  = __fadd_rn(v, __fmul_rn(__fsub_rn(xv, v), 0.5f));
        bool sp = (h >= 1.0f);
        v = sp ? 0.0f : h;
        unsigned long long msk = __ballot(sp ? 1 : 0);
        if ((threadIdx.x & 63) == 0)
            bout[((size_t)tb * CC + c) * 8 + (n >> 6)] = msk;
    }
}

// -----------------------------------------------------------------------------
// Kernel 2: attention via M = K^T V (16x16 integer popcounts), Y = 0.25 * Q M.
// Exact integer arithmetic. grid 512 (tb*16+h), block 256.
// -----------------------------------------------------------------------------
__global__ __launch_bounds__(256)
void attn_kernel(const unsigned long long* __restrict__ bq,
                 const unsigned long long* __restrict__ bk,
                 const unsigned long long* __restrict__ bv,
                 float* __restrict__ y) // [32,C,N]
{
    const int blk = blockIdx.x;
    const int h  = blk & 15;
    const int tb = blk >> 4;
    const int tid = threadIdx.x;

    __shared__ unsigned long long kb[16][8], vb[16][8], qb[16][8];
    __shared__ float M[16][16];

    size_t base = ((size_t)tb * CC + h * HD) * 8;
    if (tid < 128) {
        int j = tid >> 3, ch = tid & 7;
        kb[j][ch] = bk[base + j * 8 + ch];
        vb[j][ch] = bv[base + j * 8 + ch];
        qb[j][ch] = bq[base + j * 8 + ch];
    }
    __syncthreads();

    {
        int j = tid >> 4, d = tid & 15;
        int cnt = 0;
#pragma unroll
        for (int ch = 0; ch < 8; ++ch)
            cnt += __popcll(kb[j][ch] & vb[d][ch]);
        M[j][d] = (float)cnt;
    }
    __syncthreads();

    size_t ybase = ((size_t)tb * CC + h * HD) * (size_t)NN;
#pragma unroll
    for (int r = 0; r < 2; ++r) {
        int n = tid + 256 * r;
        int ch = n >> 6, sh = n & 63;
        float acc[16];
#pragma unroll
        for (int d = 0; d < 16; ++d) acc[d] = 0.0f;
#pragma unroll
        for (int j = 0; j < 16; ++j) {
            float bit = (float)((qb[j][ch] >> sh) & 1ULL);
#pragma unroll
            for (int d = 0; d < 16; ++d)
                acc[d] = __fmaf_rn(bit, M[j][d], acc[d]);
        }
#pragma unroll
        for (int d = 0; d < 16; ++d)
            y[ybase + (size_t)d * NN + n] = __fmul_rn(acc[d], 0.25f);
    }
}

// -----------------------------------------------------------------------------
// Kernel 3: attn LIF (v_th=0.5) in-place on y, spikes stored as 1.0f/0.0f.
// grid 512, block 256: one (c,n) chain of 32 steps per thread.
// -----------------------------------------------------------------------------
__global__ __launch_bounds__(256)
void attn_lif(float* __restrict__ y)
{
    const int e = blockIdx.x * 256 + threadIdx.x; // < 131072
    float xs[32];
#pragma unroll
    for (int tb = 0; tb < 32; ++tb)
        xs[tb] = y[(size_t)tb * (CC * NN) + e];
    float v = 0.0f;
#pragma unroll
    for (int tb = 0; tb < 32; ++tb) {
        float h = __fadd_rn(v, __fmul_rn(__fsub_rn(xs[tb], v), 0.5f));
        bool sp = (h >= 0.5f);
        y[(size_t)tb * (CC * NN) + e] = sp ? 1.0f : 0.0f;
        v = sp ? 0.0f : h;
    }
}

// -----------------------------------------------------------------------------
// Kernel 4: proj conv + BN, t-parallel. 128(o) x 64(n) tiles, 8x4 per thread.
// BK=16 dbuf, LDS 24 KB -> 512 blocks = 2/CU resident with headroom.
// grid (8, 2, 32).
// -----------------------------------------------------------------------------
__global__ __launch_bounds__(256)
void proj_gemm_bn(const float* __restrict__ X,   // [32][C][N] float spikes
                  const float* __restrict__ wtp, // [C][C] k-major (proj)
                  const float* __restrict__ scP, // [C]
                  const float* __restrict__ biP,
                  float* __restrict__ Y)         // [32][C][N]
{
    __shared__ float Wl[2][16][128];  // 16 KB
    __shared__ float Xl[2][16][64];   //  8 KB

    const int tid = threadIdx.x;
    const int tx = tid & 15;
    const int ty = tid >> 4;
    const int tb = blockIdx.z;
    const int o0 = blockIdx.y * 128;
    const int n0 = blockIdx.x * 64;

    const float* xb = X + (size_t)tb * (CC * NN);

    auto stage = [&](int s, int buf) {
        const int k0 = s * 16;
#pragma unroll
        for (int i = 0; i < 2; ++i) {
            int idx = tid + 256 * i;          // 0..511
            int row = idx >> 5, cg = idx & 31;
            GLL16(&wtp[(size_t)(k0 + row) * CC + o0 + cg * 4], &Wl[buf][row][cg * 4]);
        }
        {
            int idx = tid;                    // 0..255
            int row = idx >> 4, cg = idx & 15;
            GLL16(&xb[(size_t)(k0 + row) * NN + n0 + cg * 4], &Xl[buf][row][cg * 4]);
        }
    };

    float acc[8][4];
#pragma unroll
    for (int i = 0; i < 8; ++i)
#pragma unroll
        for (int j = 0; j < 4; ++j) acc[i][j] = 0.0f;

    stage(0, 0);
    __syncthreads();

    int cur = 0;
    for (int s = 0; s < 16; ++s) {
        if (s < 15) stage(s + 1, cur ^ 1);

#pragma unroll 8
        for (int kk = 0; kk < 16; ++kk) {
            const float4 w0 = *reinterpret_cast<const float4*>(&Wl[cur][kk][ty * 8]);
            const float4 w1 = *reinterpret_cast<const float4*>(&Wl[cur][kk][ty * 8 + 4]);
            const float4 xv = *reinterpret_cast<const float4*>(&Xl[cur][kk][tx * 4]);
            const float wa[8] = {w0.x, w0.y, w0.z, w0.w, w1.x, w1.y, w1.z, w1.w};
            const float xa[4] = {xv.x, xv.y, xv.z, xv.w};
#pragma unroll
            for (int i = 0; i < 8; ++i)
#pragma unroll
                for (int j = 0; j < 4; ++j)
                    acc[i][j] = __fmaf_rn(wa[i], xa[j], acc[i][j]);
        }

        __syncthreads();
        cur ^= 1;
    }

    float* Yp = Y + (size_t)tb * (CC * NN);
#pragma unroll
    for (int i = 0; i < 8; ++i) {
        const float sc = scP[o0 + ty * 8 + i];
        const float bi = biP[o0 + ty * 8 + i];
        float r[4];
#pragma unroll
        for (int j = 0; j < 4; ++j)
            r[j] = __fadd_rn(__fmul_rn(acc[i][j], sc), bi);
        *reinterpret_cast<float4*>(&Yp[(size_t)(o0 + ty * 8 + i) * NN + n0 + tx * 4])
            = make_float4(r[0], r[1], r[2], r[3]);
    }
}

// -----------------------------------------------------------------------------
// Kernel 5: final LIF(v_th=1) over T=4, float4-vectorized, writes 1.0f/0.0f.
// grid 1024, block 256.
// -----------------------------------------------------------------------------
__global__ __launch_bounds__(256)
void final_lif(const float* __restrict__ Yp, float* __restrict__ out)
{
    const size_t stride = (size_t)BB * CC * NN;     // 1048576
    const int i4 = blockIdx.x * 256 + threadIdx.x;  // < 262144
    float4 v = make_float4(0.f, 0.f, 0.f, 0.f);
#pragma unroll
    for (int t = 0; t < 4; ++t) {
        float4 xv = *reinterpret_cast<const float4*>(&Yp[t * stride + (size_t)i4 * 4]);
        float4 o4;
        float h;
        h = __fadd_rn(v.x, __fmul_rn(__fsub_rn(xv.x, v.x), 0.5f));
        o4.x = (h >= 1.0f) ? 1.0f : 0.0f; v.x = (h >= 1.0f) ? 0.0f : h;
        h = __fadd_rn(v.y, __fmul_rn(__fsub_rn(xv.y, v.y), 0.5f));
        o4.y = (h >= 1.0f) ? 1.0f : 0.0f; v.y = (h >= 1.0f) ? 0.0f : h;
        h = __fadd_rn(v.z, __fmul_rn(__fsub_rn(xv.z, v.z), 0.5f));
        o4.z = (h >= 1.0f) ? 1.0f : 0.0f; v.z = (h >= 1.0f) ? 0.0f : h;
        h = __fadd_rn(v.w, __fmul_rn(__fsub_rn(xv.w, v.w), 0.5f));
        o4.w = (h >= 1.0f) ? 1.0f : 0.0f; v.w = (h >= 1.0f) ? 0.0f : h;
        *reinterpret_cast<float4*>(&out[t * stride + (size_t)i4 * 4]) = o4;
    }
}

// -----------------------------------------------------------------------------
extern "C" void kernel_launch(void* const* d_in, const int* in_sizes, int n_in,
                              void* d_out, int out_size, void* d_ws, size_t ws_size,
                              hipStream_t stream) {
    const float* x = (const float*)d_in[0];

    WPtrs wp;
    BnPtrs bp;
    for (int m = 0; m < 4; ++m) {
        wp.w[m] = (const float*)d_in[1 + m * 5 + 0];
        bp.g[m] = (const float*)d_in[1 + m * 5 + 1];
        bp.b[m] = (const float*)d_in[1 + m * 5 + 2];
        bp.m[m] = (const float*)d_in[1 + m * 5 + 3];
        bp.v[m] = (const float*)d_in[1 + m * 5 + 4];
    }

    // Workspace layout (~50.6 MB):
    //   wt 1 MB | scA 4 KB | biA 4 KB | bits 1.5 MB | big 48 MB
    //   big: ybn3 [3][32][C][N] f32 (48 MB), dead after qkv_lif_pack;
    //        then ybuf (attn, 16 MB) aliases big+0 and ybn_p aliases big+16MB.
    char* ws = (char*)d_ws;
    float* wt   = (float*)ws;
    float* scA  = (float*)(ws + (1u << 20));
    float* biA  = (float*)(ws + (1u << 20) + 4096);
    unsigned long long* bits = (unsigned long long*)(ws + (1u << 20) + 8192);
    char*  big  = ws + (1u << 20) + 8192 + 1572864;
    float* ybn3 = (float*)big;                       // 48 MB
    float* ybuf = (float*)big;                       // 16 MB (after ybn3 dead)
    float* ybn_p = (float*)(big + (16u << 20));      // 16 MB

    prep_w_bn<<<dim3(16, 16, 4), dim3(16, 16), 0, stream>>>(wp, bp, wt, scA, biA);

    qkv_gemm_bn<<<dim3(4, 2, 96), 256, 0, stream>>>(x, wt, scA, biA, ybn3);
    qkv_lif_pack<<<12288, 256, 0, stream>>>(ybn3, bits);

    const unsigned long long* bq = bits;
    const unsigned long long* bk = bits + 65536;
    const unsigned long long* bv = bits + 131072;
    attn_kernel<<<512, 256, 0, stream>>>(bq, bk, bv, ybuf);
    attn_lif<<<512, 256, 0, stream>>>(ybuf);

    proj_gemm_bn<<<dim3(8, 2, 32), 256, 0, stream>>>(
        ybuf, wt + 3 * CC * CC, scA + 3 * CC, biA + 3 * CC, ybn_p);
    final_lif<<<1024, 256, 0, stream>>>(ybn_p, (float*)d_out);
}